// Round 8
// baseline (301.070 us; speedup 1.0000x reference)
//
#include <hip/hip_runtime.h>
#include <hip/hip_bf16.h>
#include <math.h>

#define Dm 1024
#define Tm 2048
#define Bm 2
#define Hm 16
#define HDm 64
#define Rm (Bm*Tm)   // 4096 rows
#define QKS 2048     // q|k row stride (dense, V split out)

typedef __attribute__((ext_vector_type(8))) short sh8;      // 8 bf16 (4 VGPRs)
typedef __attribute__((ext_vector_type(4))) float f32x4;    // 16x16 C/D frag
typedef __attribute__((ext_vector_type(16))) float f32x16;  // 32x32 C/D frag

#define AS1(p) ((const __attribute__((address_space(1))) void*)(p))
#define AS3(p) ((__attribute__((address_space(3))) void*)(p))

// fp32 -> bf16 bits, round-to-nearest-even
__device__ __forceinline__ short f2bs(float f) {
    union { float f; unsigned u; } v; v.f = f;
    unsigned r = v.u + 0x7FFFu + ((v.u >> 16) & 1u);
    return (short)(r >> 16);
}

// ---------------- weight convert: wq,wk,wv -> wqkv (bf16), wo -> wob ----
// wq pre-scaled by 0.125 (1/sqrt(64)): exact (pow2 commutes with rounding).
__global__ __launch_bounds__(256) void convert_w(const float* __restrict__ wq,
                                                 const float* __restrict__ wk,
                                                 const float* __restrict__ wv,
                                                 const float* __restrict__ wo,
                                                 short* __restrict__ wqkv,
                                                 short* __restrict__ wob) {
    int idx = (blockIdx.x * 256 + threadIdx.x) * 4;   // 4 elems/thread, 4M total
    const int M1 = 1 << 20;
    const float* src; short* dst; int off; float sc = 1.0f;
    if (idx < M1)           { src = wq; dst = wqkv;          off = idx; sc = 0.125f; }
    else if (idx < 2*M1)    { src = wk; dst = wqkv + M1;     off = idx - M1; }
    else if (idx < 3*M1)    { src = wv; dst = wqkv + 2*M1;   off = idx - 2*M1; }
    else                    { src = wo; dst = wob;           off = idx - 3*M1; }
    float4 v = *(const float4*)(src + off);
    short4 o;
    o.x = f2bs(v.x*sc); o.y = f2bs(v.y*sc); o.z = f2bs(v.z*sc); o.w = f2bs(v.w*sc);
    *(short4*)(dst + off) = o;
}

// ---------------- LayerNorm: one block (256 thr) per row, bf16 out ------
__global__ __launch_bounds__(256) void ln_kernel(const float* __restrict__ x,
                                                 const float* __restrict__ scale,
                                                 short* __restrict__ out) {
    int row = blockIdx.x;
    int t = threadIdx.x;
    const float4* xr = (const float4*)(x + (size_t)row * Dm);
    float4 v = xr[t];
    float s  = v.x + v.y + v.z + v.w;
    float ss = v.x*v.x + v.y*v.y + v.z*v.z + v.w*v.w;
    #pragma unroll
    for (int off = 32; off; off >>= 1) {
        s  += __shfl_xor(s, off);
        ss += __shfl_xor(ss, off);
    }
    __shared__ float red[8];
    int wave = t >> 6, lane = t & 63;
    if (lane == 0) { red[wave*2] = s; red[wave*2+1] = ss; }
    __syncthreads();
    s  = red[0] + red[2] + red[4] + red[6];
    ss = red[1] + red[3] + red[5] + red[7];
    float mean = s * (1.0f / Dm);
    float var  = ss * (1.0f / Dm) - mean * mean;
    float rstd = 1.0f / sqrtf(var + 1e-5f);
    float4 sc = ((const float4*)scale)[t];
    short4 o;
    o.x = f2bs(sc.x * ((v.x - mean) * rstd) + sc.x);
    o.y = f2bs(sc.y * ((v.y - mean) * rstd) + sc.y);
    o.z = f2bs(sc.z * ((v.z - mean) * rstd) + sc.z);
    o.w = f2bs(sc.w * ((v.w - mean) * rstd) + sc.w);
    ((short4*)(out + (size_t)row * Dm))[t] = o;
}

// ---------------- MFMA GEMM (m97 structure): C = A @ B^T ----------------
// MODE 0: float out + bias + residual (proj GEMM)
// MODE 1: QKV gemm: n<2048 -> bf16 into qk buffer (stride 2048);
//         n>=2048 -> V stored transposed per head AND key-permuted within
//         each 16-key group (pi: quads 1<->2) so attn's PV A-frag is
//         lane-local: vtg[bh][d][key'].
template<int BN, int MODE>
__global__ __launch_bounds__(256) void gemm_mfma(const short* __restrict__ A,
                                                 const short* __restrict__ B,
                                                 const float* __restrict__ bias,
                                                 const float* __restrict__ res,
                                                 void* __restrict__ Cv,
                                                 short* __restrict__ Vt,
                                                 int M, int N, int K) {
    __shared__ short As[128*32];
    __shared__ short Bs[BN*32];
    __shared__ short Tb[(MODE==1) ? 4*16*68 : 4];   // per-wave transpose bounce
    const int NJ = BN / 32;            // 16x16 j-tiles per wave
    int t = threadIdx.x;
    int lane = t & 63, w = t >> 6;
    int l = lane & 15, quad = lane >> 4;
    int wm = (w & 1) * 64, wn = (w >> 1) * (BN/2);
    int m0 = blockIdx.y * 128, n0 = blockIdx.x * BN;

    f32x4 acc[4][NJ];
    #pragma unroll
    for (int i = 0; i < 4; i++)
        #pragma unroll
        for (int j = 0; j < NJ; j++)
            acc[i][j] = (f32x4){0.f,0.f,0.f,0.f};

    for (int k0 = 0; k0 < K; k0 += 32) {
        __syncthreads();
        #pragma unroll
        for (int p = 0; p < 2; p++) {            // A tile: 128 rows
            int off = p*4096 + t*16;             // LDS byte offset
            int row = off >> 6;
            int c = ((off >> 4) & 3) ^ (row & 3);
            const short* ga = A + (size_t)(m0 + row) * K + k0 + c*8;
            __builtin_amdgcn_global_load_lds(AS1(ga), AS3((char*)As + off), 16, 0, 0);
        }
        #pragma unroll
        for (int p = 0; p < BN/64; p++) {        // B tile: BN rows
            int off = p*4096 + t*16;
            int row = off >> 6;
            int c = ((off >> 4) & 3) ^ (row & 3);
            const short* gb = B + (size_t)(n0 + row) * K + k0 + c*8;
            __builtin_amdgcn_global_load_lds(AS1(gb), AS3((char*)Bs + off), 16, 0, 0);
        }
        __syncthreads();
        sh8 af[4], bf[NJ];
        #pragma unroll
        for (int i = 0; i < 4; i++) {
            int m = wm + i*16 + l;
            af[i] = *(const sh8*)((const char*)As + m*64 + ((quad ^ (m & 3)) * 16));
        }
        #pragma unroll
        for (int j = 0; j < NJ; j++) {
            int n = wn + j*16 + l;
            bf[j] = *(const sh8*)((const char*)Bs + n*64 + ((quad ^ (n & 3)) * 16));
        }
        #pragma unroll
        for (int i = 0; i < 4; i++)
            #pragma unroll
            for (int j = 0; j < NJ; j++)
                acc[i][j] = __builtin_amdgcn_mfma_f32_16x16x32_bf16(af[i], bf[j], acc[i][j], 0, 0, 0);
    }
    // epilogue
    if (MODE == 0) {
        #pragma unroll
        for (int i = 0; i < 4; i++)
            #pragma unroll
            for (int j = 0; j < NJ; j++)
                #pragma unroll
                for (int r = 0; r < 4; r++) {
                    int m = m0 + wm + i*16 + quad*4 + r;
                    int n = n0 + wn + j*16 + l;
                    float vv = acc[i][j][r] + bias[n] + res[(size_t)m * N + n];
                    ((float*)Cv)[(size_t)m * N + n] = vv;
                }
    } else {
        if (n0 < 2048) {
            // q,k part: bf16 store at dense stride 2048
            #pragma unroll
            for (int i = 0; i < 4; i++)
                #pragma unroll
                for (int j = 0; j < NJ; j++)
                    #pragma unroll
                    for (int r = 0; r < 4; r++) {
                        int m = m0 + wm + i*16 + quad*4 + r;
                        int n = n0 + wn + j*16 + l;
                        ((short*)Cv)[(size_t)m * QKS + n] = f2bs(acc[i][j][r]);
                    }
        } else {
            // V part: transpose + pi-permute -> vtg[bh][d][key']
            // pi swaps sub-positions 4-7 <-> 8-11 per 16-key group: quad' =
            // bit-swap(quad) (0->0, 1->2, 2->1, 3->3).
            int bq = m0 >> 11;                    // batch
            int key0 = (m0 & 2047) + wm;          // wave's key base
            int h = (n0 + wn - 2048) >> 6;        // wave covers exactly one head
            int quad2 = ((quad & 1) << 1) | (quad >> 1);
            short* vout = Vt + ((size_t)(bq*Hm + h) * HDm) * Tm + key0;
            #pragma unroll
            for (int j = 0; j < NJ; j++) {
                #pragma unroll
                for (int i = 0; i < 4; i++) {
                    short4 o;
                    o.x = f2bs(acc[i][j][0]); o.y = f2bs(acc[i][j][1]);
                    o.z = f2bs(acc[i][j][2]); o.w = f2bs(acc[i][j][3]);
                    *(short4*)&Tb[w*(16*68) + l*68 + i*16 + quad2*4] = o;
                }
                #pragma unroll
                for (int st = 0; st < 2; st++) {
                    int rr = st*8 + (lane >> 3);
                    int cc = lane & 7;
                    sh8 vv = *(const sh8*)&Tb[w*(16*68) + rr*68 + cc*8];
                    *(sh8*)(vout + (size_t)(j*16 + rr) * Tm + cc*8) = vv;
                }
            }
        }
    }
}

// ---------------- MFMA flash attention, 32x32 S^T, lane-local P ---------
// v8 = v7 + cross-chunk software pipeline. Per iteration:
//   exp/pack(kc) -> barrier -> STAGE_K(kc+2) -> STAGE_V(kc+1)
//   -> QK(kc+1) -> PV(kc)
// K ring = 3 bufs (staged 2 ahead), V = 2 bufs (staged 1 ahead): every
// global_load_lds has a full chunk of compute before the barrier that
// drains it (no same-iteration vmcnt stall), and QK(kc+1) overlaps PV(kc)
// in the MFMA pipe (independent accumulators). LDS = 24+16 = 40 KB ->
// 4 blocks/CU, balanced-qt table, XCD = bh%8 unchanged.
// Race audit: STAGE_K(kc+2) overwrites Kl[(kc-1)%3] (last read: QK(kc-1),
// two barriers ago); STAGE_V(kc+1) overwrites Vl[(kc-1)&1] (last read:
// PV(kc-1), completed by every wave before barrier(kc)). Safe.
__global__ __launch_bounds__(128) void attn_mfma(const short* __restrict__ qk,
                                                 const short* __restrict__ vtg,
                                                 short* __restrict__ ctx) {
    __shared__ short Kl[3][64*64];     // 24 KB: XOR-swizzled, 3-ring
    __shared__ short Vl[2][64*64];     // 16 KB: V^T permuted, swizzled, dbuf
    int t = threadIdx.x;               // 0..127
    int lane = t & 63, w = t >> 6;     // 2 waves
    int l31 = lane & 31, hi = lane >> 5;
    int bh = blockIdx.x;               // 0..31 (XCD = bh%8)
    int xi = blockIdx.y;               // 0..31
    int cc0 = xi & 7, kk0 = xi >> 3;
    int qt = (kk0 == 0) ? cc0 : (kk0 == 1) ? (15 - cc0)
           : (kk0 == 2) ? (16 + cc0) : (31 - cc0);
    int b = bh >> 4, h = bh & 15;
    size_t rbase = (size_t)b * Tm;
    const short* qp0 = qk + rbase * QKS + h*HDm;
    const short* kp0 = qp0 + Dm;
    const short* vh  = vtg + ((size_t)bh * HDm) * Tm;
    int qtbase = qt * 64;
    int qrow = qtbase + w*32 + l31;

    // Q B-frags: qf[s] = Q[q=l31][d = s*16 + hi*8 + j]
    sh8 qf[4];
    {
        const short* qp = qp0 + (size_t)qrow * QKS + hi*8;
        qf[0] = *(const sh8*)qp;
        qf[1] = *(const sh8*)(qp + 16);
        qf[2] = *(const sh8*)(qp + 32);
        qf[3] = *(const sh8*)(qp + 48);
    }

    f32x16 O0, O1;
    #pragma unroll
    for (int i = 0; i < 16; i++) { O0[i] = 0.f; O1[i] = 0.f; }
    float ps = 0.f;

    // ---- staging addresses (advance by constants per STAGE) ----
    int trow = t >> 3;                       // 0..15
    int c8 = ((t & 7) ^ (trow & 7)) * 8;     // swizzled chunk (shorts)
    int ldsoff = t * 16;                     // bytes
    const short* gkp = kp0 + (size_t)trow * QKS + c8;
    const short* gvp = vh + (size_t)trow * Tm + c8;

#define STAGE_K(KD) do { \
    __builtin_amdgcn_global_load_lds(AS1(gkp),                  AS3((char*)(KD) + ldsoff), 16, 0, 0); \
    __builtin_amdgcn_global_load_lds(AS1(gkp + (size_t)16*QKS), AS3((char*)(KD) + 2048 + ldsoff), 16, 0, 0); \
    __builtin_amdgcn_global_load_lds(AS1(gkp + (size_t)32*QKS), AS3((char*)(KD) + 4096 + ldsoff), 16, 0, 0); \
    __builtin_amdgcn_global_load_lds(AS1(gkp + (size_t)48*QKS), AS3((char*)(KD) + 6144 + ldsoff), 16, 0, 0); \
    gkp += (size_t)64*QKS; } while (0)

#define STAGE_V(VD) do { \
    __builtin_amdgcn_global_load_lds(AS1(gvp),                 AS3((char*)(VD) + ldsoff), 16, 0, 0); \
    __builtin_amdgcn_global_load_lds(AS1(gvp + (size_t)16*Tm), AS3((char*)(VD) + 2048 + ldsoff), 16, 0, 0); \
    __builtin_amdgcn_global_load_lds(AS1(gvp + (size_t)32*Tm), AS3((char*)(VD) + 4096 + ldsoff), 16, 0, 0); \
    __builtin_amdgcn_global_load_lds(AS1(gvp + (size_t)48*Tm), AS3((char*)(VD) + 6144 + ldsoff), 16, 0, 0); \
    gvp += 64; } while (0)

// QK for one chunk from KBUF into S0,S1 (keys kt*32+l31; slot sw = l31&7)
#define QKCOMP(KBUF) do { \
    const char* Kb_ = (const char*)(KBUF); \
    int sw_ = l31 & 7; \
    { const char* kr = Kb_ + l31*128; \
      f32x16 c; \
      _Pragma("unroll") for (int i_ = 0; i_ < 16; i_++) c[i_] = 0.f; \
      _Pragma("unroll") for (int s_ = 0; s_ < 4; s_++) { \
          sh8 kf = *(const sh8*)(kr + (((s_*2 + hi) ^ sw_) * 16)); \
          c = __builtin_amdgcn_mfma_f32_32x32x16_bf16(kf, qf[s_], c, 0, 0, 0); } \
      S0 = c; } \
    { const char* kr = Kb_ + (32 + l31)*128; \
      f32x16 c; \
      _Pragma("unroll") for (int i_ = 0; i_ < 16; i_++) c[i_] = 0.f; \
      _Pragma("unroll") for (int s_ = 0; s_ < 4; s_++) { \
          sh8 kf = *(const sh8*)(kr + (((s_*2 + hi) ^ sw_) * 16)); \
          c = __builtin_amdgcn_mfma_f32_32x32x16_bf16(kf, qf[s_], c, 0, 0, 0); } \
      S1 = c; } \
} while (0)

    // ---- prologue ----
    STAGE_K(Kl[0]);
    STAGE_V(Vl[0]);
    if (qt >= 1) STAGE_K(Kl[1]);
    __syncthreads();

    f32x16 S0, S1;
    QKCOMP(Kl[0]);

    int bcur = 0;                      // K-ring index of chunk kc
    for (int kc = 0; kc <= qt; kc++) {
        int kbase = kc * 64;
        // ---- exp/pack chunk kc (S0: keys kbase+0..31, S1: +32..63) ----
        sh8 pa[4];
        {
            bool needmask = (kbase + 63 > qtbase + w*32);
            float p_[16];
            // kt = 0
            if (needmask) {
                #pragma unroll
                for (int r = 0; r < 16; r++) {
                    int key_r = kbase + (r&3) + 8*(r>>2) + 4*hi;
                    p_[r] = (key_r > qrow) ? 0.f : __expf(S0[r]);
                }
            } else {
                #pragma unroll
                for (int r = 0; r < 16; r++) p_[r] = __expf(S0[r]);
            }
            ps += (((p_[0]+p_[1])+(p_[2]+p_[3])) + ((p_[4]+p_[5])+(p_[6]+p_[7])))
                + (((p_[8]+p_[9])+(p_[10]+p_[11])) + ((p_[12]+p_[13])+(p_[14]+p_[15])));
            #pragma unroll
            for (int gg = 0; gg < 2; gg++) {
                union { __hip_bfloat162 h2[4]; sh8 s8; } u;
                u.h2[0] = __float22bfloat162_rn({p_[gg*8+0], p_[gg*8+1]});
                u.h2[1] = __float22bfloat162_rn({p_[gg*8+2], p_[gg*8+3]});
                u.h2[2] = __float22bfloat162_rn({p_[gg*8+4], p_[gg*8+5]});
                u.h2[3] = __float22bfloat162_rn({p_[gg*8+6], p_[gg*8+7]});
                pa[gg] = u.s8;
            }
            // kt = 1
            if (needmask) {
                #pragma unroll
                for (int r = 0; r < 16; r++) {
                    int key_r = kbase + 32 + (r&3) + 8*(r>>2) + 4*hi;
                    p_[r] = (key_r > qrow) ? 0.f : __expf(S1[r]);
                }
            } else {
                #pragma unroll
                for (int r = 0; r < 16; r++) p_[r] = __expf(S1[r]);
            }
            ps += (((p_[0]+p_[1])+(p_[2]+p_[3])) + ((p_[4]+p_[5])+(p_[6]+p_[7])))
                + (((p_[8]+p_[9])+(p_[10]+p_[11])) + ((p_[12]+p_[13])+(p_[14]+p_[15])));
            #pragma unroll
            for (int gg = 0; gg < 2; gg++) {
                union { __hip_bfloat162 h2[4]; sh8 s8; } u;
                u.h2[0] = __float22bfloat162_rn({p_[gg*8+0], p_[gg*8+1]});
                u.h2[1] = __float22bfloat162_rn({p_[gg*8+2], p_[gg*8+3]});
                u.h2[2] = __float22bfloat162_rn({p_[gg*8+4], p_[gg*8+5]});
                u.h2[3] = __float22bfloat162_rn({p_[gg*8+6], p_[gg*8+7]});
                pa[2 + gg] = u.s8;
            }
        }

        // ---- barrier: drains K(kc+1) and V(kc), both issued last iter ----
        __syncthreads();

        // ---- prefetch 2-ahead K, 1-ahead V (drained NEXT barrier) ----
        int bnext = (bcur == 2) ? 0 : bcur + 1;       // ring idx of kc+1
        if (kc + 2 <= qt) {
            int bnext2 = (bnext == 2) ? 0 : bnext + 1;
            STAGE_K(Kl[bnext2]);
        }
        if (kc + 1 <= qt) STAGE_V(Vl[(kc + 1) & 1]);

        // ---- QK(kc+1): overlaps PV(kc) in the MFMA pipe ----
        if (kc < qt) QKCOMP(Kl[bnext]);

        // ---- O += P V (V in pi-permuted key order) ----
        const char* Vb = (const char*)Vl[kc & 1];
        {
            const char* vr = Vb + l31*128;
            int sw = l31 & 7;
            #pragma unroll
            for (int G = 0; G < 4; G++) {
                sh8 vf = *(const sh8*)(vr + (((G*2 + hi) ^ sw) * 16));
                O0 = __builtin_amdgcn_mfma_f32_32x32x16_bf16(pa[G], vf, O0, 0, 0, 0);
            }
        }
        {
            const char* vr = Vb + (32 + l31)*128;
            int sw = l31 & 7;
            #pragma unroll
            for (int G = 0; G < 4; G++) {
                sh8 vf = *(const sh8*)(vr + (((G*2 + hi) ^ sw) * 16));
                O1 = __builtin_amdgcn_mfma_f32_32x32x16_bf16(pa[G], vf, O1, 0, 0, 0);
            }
        }
        bcur = bnext;
    }
#undef STAGE_K
#undef STAGE_V
#undef QKCOMP

    // ---- epilogue: lane's ps covers its 32 keys of col q=l31 ----
    ps += __shfl_xor(ps, 32);          // full denominator for q=l31
    float inv_own = 1.0f / ps;
    short* cp = ctx + (rbase + qtbase + w*32) * Dm + h*HDm + l31;
    #pragma unroll
    for (int r = 0; r < 16; r++) {
        int rl = (r&3) + 8*(r>>2) + 4*hi;          // q-row local 0..31
        float inv = __shfl(inv_own, rl);           // from lane rl (col q=rl)
        cp[(size_t)rl * Dm]      = f2bs(O0[r] * inv);
        cp[(size_t)rl * Dm + 32] = f2bs(O1[r] * inv);
    }
}

// ---------------- launch ----------------
extern "C" void kernel_launch(void* const* d_in, const int* in_sizes, int n_in,
                              void* d_out, int out_size, void* d_ws, size_t ws_size,
                              hipStream_t stream) {
    const float* x   = (const float*)d_in[0];
    const float* wq  = (const float*)d_in[1];
    const float* wk  = (const float*)d_in[2];
    const float* wv  = (const float*)d_in[3];
    const float* wo  = (const float*)d_in[4];
    const float* bo  = (const float*)d_in[5];
    const float* ln1 = (const float*)d_in[6];
    const float* ln2 = (const float*)d_in[7];
    float* out = (float*)d_out;

    short* lnb  = (short*)d_ws;                      // 4096*1024 = 4M sh
    short* ctxb = lnb  + (size_t)Rm*Dm;              // 4M sh
    short* qk   = ctxb + (size_t)Rm*Dm;              // 8M sh
    short* vtg  = qk   + (size_t)Rm*QKS;             // 4M sh
    short* wqkv = vtg  + (size_t)Bm*Hm*HDm*Tm;       // 3M sh
    short* wob  = wqkv + (size_t)3*Dm*Dm;            // 1M sh

    dim3 qgrid(3072/128, Rm/128);  // (24, 32)
    dim3 pgrid(Dm/64,    Rm/128);  // (16, 32): proj BN=64 (round-4 proven)
    dim3 agrid(32, 32);            // (bh, xi), balanced qt table, 128-thr

    convert_w<<<4096, 256, 0, stream>>>(wq, wk, wv, wo, wqkv, wob);

    // ---- Block 1 ----
    ln_kernel<<<Rm, 256, 0, stream>>>(x, ln1, lnb);
    gemm_mfma<128, 1><<<qgrid, 256, 0, stream>>>(lnb, wqkv, nullptr, nullptr, qk, vtg, Rm, 3072, Dm);
    attn_mfma<<<agrid, 128, 0, stream>>>(qk, vtg, ctxb);
    gemm_mfma<64, 0><<<pgrid, 256, 0, stream>>>(ctxb, wob, bo, x, out, nullptr, Rm, Dm, Dm);

    // ---- Block 2 (same weights, ln2) ----
    ln_kernel<<<Rm, 256, 0, stream>>>(out, ln2, lnb);
    gemm_mfma<128, 1><<<qgrid, 256, 0, stream>>>(lnb, wqkv, nullptr, nullptr, qk, vtg, Rm, 3072, Dm);
    attn_mfma<<<agrid, 128, 0, stream>>>(qk, vtg, ctxb);
    gemm_mfma<64, 0><<<pgrid, 256, 0, stream>>>(ctxb, wob, bo, out, out, nullptr, Rm, Dm, Dm);
}

// Round 9
// 284.647 us; speedup vs baseline: 1.0577x; 1.0577x over previous
//
#include <hip/hip_runtime.h>
#include <hip/hip_bf16.h>
#include <math.h>

#define Dm 1024
#define Tm 2048
#define Bm 2
#define Hm 16
#define HDm 64
#define Rm (Bm*Tm)   // 4096 rows
#define QKS 2048     // q|k row stride (dense, V split out)

typedef __attribute__((ext_vector_type(8))) short sh8;      // 8 bf16 (4 VGPRs)
typedef __attribute__((ext_vector_type(4))) float f32x4;    // 16x16 C/D frag
typedef __attribute__((ext_vector_type(16))) float f32x16;  // 32x32 C/D frag

#define AS1(p) ((const __attribute__((address_space(1))) void*)(p))
#define AS3(p) ((__attribute__((address_space(3))) void*)(p))

// fp32 -> bf16 bits, round-to-nearest-even
__device__ __forceinline__ short f2bs(float f) {
    union { float f; unsigned u; } v; v.f = f;
    unsigned r = v.u + 0x7FFFu + ((v.u >> 16) & 1u);
    return (short)(r >> 16);
}

// ---------------- weight convert: wq,wk,wv -> wqkv (bf16), wo -> wob ----
// wq pre-scaled by 0.125 (1/sqrt(64)): exact (pow2 commutes with rounding).
__global__ __launch_bounds__(256) void convert_w(const float* __restrict__ wq,
                                                 const float* __restrict__ wk,
                                                 const float* __restrict__ wv,
                                                 const float* __restrict__ wo,
                                                 short* __restrict__ wqkv,
                                                 short* __restrict__ wob) {
    int idx = (blockIdx.x * 256 + threadIdx.x) * 4;   // 4 elems/thread, 4M total
    const int M1 = 1 << 20;
    const float* src; short* dst; int off; float sc = 1.0f;
    if (idx < M1)           { src = wq; dst = wqkv;          off = idx; sc = 0.125f; }
    else if (idx < 2*M1)    { src = wk; dst = wqkv + M1;     off = idx - M1; }
    else if (idx < 3*M1)    { src = wv; dst = wqkv + 2*M1;   off = idx - 2*M1; }
    else                    { src = wo; dst = wob;           off = idx - 3*M1; }
    float4 v = *(const float4*)(src + off);
    short4 o;
    o.x = f2bs(v.x*sc); o.y = f2bs(v.y*sc); o.z = f2bs(v.z*sc); o.w = f2bs(v.w*sc);
    *(short4*)(dst + off) = o;
}

// ---------------- LayerNorm: one block (256 thr) per row, bf16 out ------
__global__ __launch_bounds__(256) void ln_kernel(const float* __restrict__ x,
                                                 const float* __restrict__ scale,
                                                 short* __restrict__ out) {
    int row = blockIdx.x;
    int t = threadIdx.x;
    const float4* xr = (const float4*)(x + (size_t)row * Dm);
    float4 v = xr[t];
    float s  = v.x + v.y + v.z + v.w;
    float ss = v.x*v.x + v.y*v.y + v.z*v.z + v.w*v.w;
    #pragma unroll
    for (int off = 32; off; off >>= 1) {
        s  += __shfl_xor(s, off);
        ss += __shfl_xor(ss, off);
    }
    __shared__ float red[8];
    int wave = t >> 6, lane = t & 63;
    if (lane == 0) { red[wave*2] = s; red[wave*2+1] = ss; }
    __syncthreads();
    s  = red[0] + red[2] + red[4] + red[6];
    ss = red[1] + red[3] + red[5] + red[7];
    float mean = s * (1.0f / Dm);
    float var  = ss * (1.0f / Dm) - mean * mean;
    float rstd = 1.0f / sqrtf(var + 1e-5f);
    float4 sc = ((const float4*)scale)[t];
    short4 o;
    o.x = f2bs(sc.x * ((v.x - mean) * rstd) + sc.x);
    o.y = f2bs(sc.y * ((v.y - mean) * rstd) + sc.y);
    o.z = f2bs(sc.z * ((v.z - mean) * rstd) + sc.z);
    o.w = f2bs(sc.w * ((v.w - mean) * rstd) + sc.w);
    ((short4*)(out + (size_t)row * Dm))[t] = o;
}

// ---------------- MFMA GEMM (m97 structure): C = A @ B^T ----------------
// MODE 0: float out + bias + residual (proj GEMM)
// MODE 1: QKV gemm: n<2048 -> bf16 into qk buffer (stride 2048);
//         n>=2048 -> V stored transposed per head AND key-permuted within
//         each 16-key group (pi: quads 1<->2) so attn's PV A-frag is
//         lane-local: vtg[bh][d][key'].
template<int BN, int MODE>
__global__ __launch_bounds__(256) void gemm_mfma(const short* __restrict__ A,
                                                 const short* __restrict__ B,
                                                 const float* __restrict__ bias,
                                                 const float* __restrict__ res,
                                                 void* __restrict__ Cv,
                                                 short* __restrict__ Vt,
                                                 int M, int N, int K) {
    __shared__ short As[128*32];
    __shared__ short Bs[BN*32];
    __shared__ short Tb[(MODE==1) ? 4*16*68 : 4];   // per-wave transpose bounce
    const int NJ = BN / 32;            // 16x16 j-tiles per wave
    int t = threadIdx.x;
    int lane = t & 63, w = t >> 6;
    int l = lane & 15, quad = lane >> 4;
    int wm = (w & 1) * 64, wn = (w >> 1) * (BN/2);
    int m0 = blockIdx.y * 128, n0 = blockIdx.x * BN;

    f32x4 acc[4][NJ];
    #pragma unroll
    for (int i = 0; i < 4; i++)
        #pragma unroll
        for (int j = 0; j < NJ; j++)
            acc[i][j] = (f32x4){0.f,0.f,0.f,0.f};

    for (int k0 = 0; k0 < K; k0 += 32) {
        __syncthreads();
        #pragma unroll
        for (int p = 0; p < 2; p++) {            // A tile: 128 rows
            int off = p*4096 + t*16;             // LDS byte offset
            int row = off >> 6;
            int c = ((off >> 4) & 3) ^ (row & 3);
            const short* ga = A + (size_t)(m0 + row) * K + k0 + c*8;
            __builtin_amdgcn_global_load_lds(AS1(ga), AS3((char*)As + off), 16, 0, 0);
        }
        #pragma unroll
        for (int p = 0; p < BN/64; p++) {        // B tile: BN rows
            int off = p*4096 + t*16;
            int row = off >> 6;
            int c = ((off >> 4) & 3) ^ (row & 3);
            const short* gb = B + (size_t)(n0 + row) * K + k0 + c*8;
            __builtin_amdgcn_global_load_lds(AS1(gb), AS3((char*)Bs + off), 16, 0, 0);
        }
        __syncthreads();
        sh8 af[4], bf[NJ];
        #pragma unroll
        for (int i = 0; i < 4; i++) {
            int m = wm + i*16 + l;
            af[i] = *(const sh8*)((const char*)As + m*64 + ((quad ^ (m & 3)) * 16));
        }
        #pragma unroll
        for (int j = 0; j < NJ; j++) {
            int n = wn + j*16 + l;
            bf[j] = *(const sh8*)((const char*)Bs + n*64 + ((quad ^ (n & 3)) * 16));
        }
        #pragma unroll
        for (int i = 0; i < 4; i++)
            #pragma unroll
            for (int j = 0; j < NJ; j++)
                acc[i][j] = __builtin_amdgcn_mfma_f32_16x16x32_bf16(af[i], bf[j], acc[i][j], 0, 0, 0);
    }
    // epilogue
    if (MODE == 0) {
        #pragma unroll
        for (int i = 0; i < 4; i++)
            #pragma unroll
            for (int j = 0; j < NJ; j++)
                #pragma unroll
                for (int r = 0; r < 4; r++) {
                    int m = m0 + wm + i*16 + quad*4 + r;
                    int n = n0 + wn + j*16 + l;
                    float vv = acc[i][j][r] + bias[n] + res[(size_t)m * N + n];
                    ((float*)Cv)[(size_t)m * N + n] = vv;
                }
    } else {
        if (n0 < 2048) {
            // q,k part: bf16 store at dense stride 2048
            #pragma unroll
            for (int i = 0; i < 4; i++)
                #pragma unroll
                for (int j = 0; j < NJ; j++)
                    #pragma unroll
                    for (int r = 0; r < 4; r++) {
                        int m = m0 + wm + i*16 + quad*4 + r;
                        int n = n0 + wn + j*16 + l;
                        ((short*)Cv)[(size_t)m * QKS + n] = f2bs(acc[i][j][r]);
                    }
        } else {
            // V part: transpose + pi-permute -> vtg[bh][d][key']
            // pi swaps sub-positions 4-7 <-> 8-11 per 16-key group: quad' =
            // bit-swap(quad) (0->0, 1->2, 2->1, 3->3).
            int bq = m0 >> 11;                    // batch
            int key0 = (m0 & 2047) + wm;          // wave's key base
            int h = (n0 + wn - 2048) >> 6;        // wave covers exactly one head
            int quad2 = ((quad & 1) << 1) | (quad >> 1);
            short* vout = Vt + ((size_t)(bq*Hm + h) * HDm) * Tm + key0;
            #pragma unroll
            for (int j = 0; j < NJ; j++) {
                #pragma unroll
                for (int i = 0; i < 4; i++) {
                    short4 o;
                    o.x = f2bs(acc[i][j][0]); o.y = f2bs(acc[i][j][1]);
                    o.z = f2bs(acc[i][j][2]); o.w = f2bs(acc[i][j][3]);
                    *(short4*)&Tb[w*(16*68) + l*68 + i*16 + quad2*4] = o;
                }
                #pragma unroll
                for (int st = 0; st < 2; st++) {
                    int rr = st*8 + (lane >> 3);
                    int cc = lane & 7;
                    sh8 vv = *(const sh8*)&Tb[w*(16*68) + rr*68 + cc*8];
                    *(sh8*)(vout + (size_t)(j*16 + rr) * Tm + cc*8) = vv;
                }
            }
        }
    }
}

// ---------------- MFMA flash attention, 32x32 S^T, lane-local P ---------
// v9 = v8 pipeline + KEY-SPLIT WAVES: 256-thr blocks, wave (qh,kh) owns
// q-half qh (32 rows) and key-half kh (32 of each 64-key chunk). Per-block
// work identical to v8 but spread over 4 waves -> 16 waves/CU peak (was 8)
// at the same 40 KB LDS / 4 blocks/CU. Partial O/psum across kh combine
// additively in a one-time LDS epilogue (raw exp(s), no online max).
// Pipeline per iter: exp/pack(kc) -> barrier -> STAGE_K(kc+2) ->
// STAGE_V(kc+1) -> QK(kc+1) -> PV(kc). K 3-ring, V 2-ring.
__global__ __launch_bounds__(256) void attn_mfma(const short* __restrict__ qk,
                                                 const short* __restrict__ vtg,
                                                 short* __restrict__ ctx) {
    __shared__ short Kl[3][64*64];     // 24 KB: XOR-swizzled, 3-ring
    __shared__ short Vl[2][64*64];     // 16 KB: V^T permuted, swizzled, dbuf
    int t = threadIdx.x;               // 0..255
    int lane = t & 63, w = t >> 6;     // 4 waves
    int qh = w & 1, kh = w >> 1;       // q-half, key-half
    int l31 = lane & 31, hi = lane >> 5;
    int bh = blockIdx.x;               // 0..31 (XCD = bh%8)
    int xi = blockIdx.y;               // 0..31
    int cc0 = xi & 7, kk0 = xi >> 3;
    int qt = (kk0 == 0) ? cc0 : (kk0 == 1) ? (15 - cc0)
           : (kk0 == 2) ? (16 + cc0) : (31 - cc0);
    int b = bh >> 4, h = bh & 15;
    size_t rbase = (size_t)b * Tm;
    const short* qp0 = qk + rbase * QKS + h*HDm;
    const short* kp0 = qp0 + Dm;
    const short* vh  = vtg + ((size_t)bh * HDm) * Tm;
    int qtbase = qt * 64;
    int qrow = qtbase + qh*32 + l31;

    // Q B-frags: qf[s] = Q[q=l31 of half qh][d = s*16 + hi*8 + j]
    sh8 qf[4];
    {
        const short* qp = qp0 + (size_t)qrow * QKS + hi*8;
        qf[0] = *(const sh8*)qp;
        qf[1] = *(const sh8*)(qp + 16);
        qf[2] = *(const sh8*)(qp + 32);
        qf[3] = *(const sh8*)(qp + 48);
    }

    f32x16 O0, O1;
    #pragma unroll
    for (int i = 0; i < 16; i++) { O0[i] = 0.f; O1[i] = 0.f; }
    float ps = 0.f;

    // ---- staging (256 thr stage 8KB K + 8KB V per chunk, 2 loads each) --
    int trow = t >> 3;                       // 0..31
    int c8 = ((t & 7) ^ (trow & 7)) * 8;     // pre-swizzled source chunk
    int ldsoff = t * 16;                     // bytes, 0..4080
    const short* gkp = kp0 + (size_t)trow * QKS + c8;
    const short* gvp = vh + (size_t)trow * Tm + c8;

#define STAGE_K(KD) do { \
    __builtin_amdgcn_global_load_lds(AS1(gkp),                  AS3((char*)(KD) + ldsoff), 16, 0, 0); \
    __builtin_amdgcn_global_load_lds(AS1(gkp + (size_t)32*QKS), AS3((char*)(KD) + 4096 + ldsoff), 16, 0, 0); \
    gkp += (size_t)64*QKS; } while (0)

#define STAGE_V(VD) do { \
    __builtin_amdgcn_global_load_lds(AS1(gvp),                 AS3((char*)(VD) + ldsoff), 16, 0, 0); \
    __builtin_amdgcn_global_load_lds(AS1(gvp + (size_t)32*Tm), AS3((char*)(VD) + 4096 + ldsoff), 16, 0, 0); \
    gvp += 64; } while (0)

// QK for this wave's key-half from KBUF into S0 (keys kh*32 + l31)
#define QKCOMP(KBUF) do { \
    const char* kr_ = (const char*)(KBUF) + (kh*32 + l31)*128; \
    int sw_ = l31 & 7; \
    f32x16 c_; \
    _Pragma("unroll") for (int i_ = 0; i_ < 16; i_++) c_[i_] = 0.f; \
    _Pragma("unroll") for (int s_ = 0; s_ < 4; s_++) { \
        sh8 kf_ = *(const sh8*)(kr_ + (((s_*2 + hi) ^ sw_) * 16)); \
        c_ = __builtin_amdgcn_mfma_f32_32x32x16_bf16(kf_, qf[s_], c_, 0, 0, 0); } \
    S0 = c_; \
} while (0)

    // ---- prologue ----
    STAGE_K(Kl[0]);
    STAGE_V(Vl[0]);
    if (qt >= 1) STAGE_K(Kl[1]);
    __syncthreads();

    f32x16 S0;
    QKCOMP(Kl[0]);

    int bcur = 0;                      // K-ring index of chunk kc
    for (int kc = 0; kc <= qt; kc++) {
        int kbase = kc * 64;
        // ---- exp/pack chunk kc (this wave: keys kbase + kh*32 + 0..31) --
        sh8 pa[2];
        {
            bool needmask = (kbase + kh*32 + 31 > qtbase + qh*32);
            float p_[16];
            if (needmask) {
                #pragma unroll
                for (int r = 0; r < 16; r++) {
                    int key_r = kbase + kh*32 + (r&3) + 8*(r>>2) + 4*hi;
                    p_[r] = (key_r > qrow) ? 0.f : __expf(S0[r]);
                }
            } else {
                #pragma unroll
                for (int r = 0; r < 16; r++) p_[r] = __expf(S0[r]);
            }
            ps += (((p_[0]+p_[1])+(p_[2]+p_[3])) + ((p_[4]+p_[5])+(p_[6]+p_[7])))
                + (((p_[8]+p_[9])+(p_[10]+p_[11])) + ((p_[12]+p_[13])+(p_[14]+p_[15])));
            #pragma unroll
            for (int gg = 0; gg < 2; gg++) {
                union { __hip_bfloat162 h2[4]; sh8 s8; } u;
                u.h2[0] = __float22bfloat162_rn({p_[gg*8+0], p_[gg*8+1]});
                u.h2[1] = __float22bfloat162_rn({p_[gg*8+2], p_[gg*8+3]});
                u.h2[2] = __float22bfloat162_rn({p_[gg*8+4], p_[gg*8+5]});
                u.h2[3] = __float22bfloat162_rn({p_[gg*8+6], p_[gg*8+7]});
                pa[gg] = u.s8;
            }
        }

        // ---- barrier: drains K(kc+1) and V(kc), both issued last iter ----
        __syncthreads();

        // ---- prefetch 2-ahead K, 1-ahead V (drained NEXT barrier) ----
        int bnext = (bcur == 2) ? 0 : bcur + 1;       // ring idx of kc+1
        if (kc + 2 <= qt) {
            int bnext2 = (bnext == 2) ? 0 : bnext + 1;
            STAGE_K(Kl[bnext2]);
        }
        if (kc + 1 <= qt) STAGE_V(Vl[(kc + 1) & 1]);

        // ---- QK(kc+1): overlaps PV(kc) in the MFMA pipe ----
        if (kc < qt) QKCOMP(Kl[bnext]);

        // ---- O += P V over this wave's key-half (groups G = kh*2, kh*2+1)
        const char* Vb = (const char*)Vl[kc & 1];
        int G0 = kh * 2;
        {
            const char* vr = Vb + l31*128;
            int sw = l31 & 7;
            sh8 v0 = *(const sh8*)(vr + ((((G0  )*2 + hi) ^ sw) * 16));
            sh8 v1 = *(const sh8*)(vr + ((((G0+1)*2 + hi) ^ sw) * 16));
            O0 = __builtin_amdgcn_mfma_f32_32x32x16_bf16(pa[0], v0, O0, 0, 0, 0);
            O0 = __builtin_amdgcn_mfma_f32_32x32x16_bf16(pa[1], v1, O0, 0, 0, 0);
        }
        {
            const char* vr = Vb + (32 + l31)*128;
            int sw = l31 & 7;
            sh8 v0 = *(const sh8*)(vr + ((((G0  )*2 + hi) ^ sw) * 16));
            sh8 v1 = *(const sh8*)(vr + ((((G0+1)*2 + hi) ^ sw) * 16));
            O1 = __builtin_amdgcn_mfma_f32_32x32x16_bf16(pa[0], v0, O1, 0, 0, 0);
            O1 = __builtin_amdgcn_mfma_f32_32x32x16_bf16(pa[1], v1, O1, 0, 0, 0);
        }
        bcur = bnext;
    }
#undef STAGE_K
#undef STAGE_V
#undef QKCOMP

    // ---- epilogue: combine key-halves via LDS (reuse Kl/Vl), store -----
    ps += __shfl_xor(ps, 32);          // per-q-col denominator (this half)
    __syncthreads();                   // all compute done; LDS reusable
    float* Lo  = (float*)Kl;           // 16 KB: [qh][q 0..31][d 0..63]
    float* Lps = (float*)Vl;           // 64 floats
    if (kh == 1) {
        #pragma unroll
        for (int r = 0; r < 16; r++) {
            int rl = (r&3) + 8*(r>>2) + 4*hi;
            Lo[qh*2048 + rl*64 + l31]      = O0[r];
            Lo[qh*2048 + rl*64 + 32 + l31] = O1[r];
        }
        if (hi == 0) Lps[qh*32 + l31] = ps;
    }
    __syncthreads();
    if (kh == 0) {
        float pst = ps + Lps[qh*32 + l31];
        float inv_own = 1.0f / pst;
        short* cp = ctx + (rbase + qtbase + qh*32) * Dm + h*HDm + l31;
        #pragma unroll
        for (int r = 0; r < 16; r++) {
            int rl = (r&3) + 8*(r>>2) + 4*hi;
            float inv = __shfl(inv_own, rl);
            cp[(size_t)rl * Dm]      = f2bs((O0[r] + Lo[qh*2048 + rl*64 + l31]) * inv);
            cp[(size_t)rl * Dm + 32] = f2bs((O1[r] + Lo[qh*2048 + rl*64 + 32 + l31]) * inv);
        }
    }
}

// ---------------- launch ----------------
extern "C" void kernel_launch(void* const* d_in, const int* in_sizes, int n_in,
                              void* d_out, int out_size, void* d_ws, size_t ws_size,
                              hipStream_t stream) {
    const float* x   = (const float*)d_in[0];
    const float* wq  = (const float*)d_in[1];
    const float* wk  = (const float*)d_in[2];
    const float* wv  = (const float*)d_in[3];
    const float* wo  = (const float*)d_in[4];
    const float* bo  = (const float*)d_in[5];
    const float* ln1 = (const float*)d_in[6];
    const float* ln2 = (const float*)d_in[7];
    float* out = (float*)d_out;

    short* lnb  = (short*)d_ws;                      // 4096*1024 = 4M sh
    short* ctxb = lnb  + (size_t)Rm*Dm;              // 4M sh
    short* qk   = ctxb + (size_t)Rm*Dm;              // 8M sh
    short* vtg  = qk   + (size_t)Rm*QKS;             // 4M sh
    short* wqkv = vtg  + (size_t)Bm*Hm*HDm*Tm;       // 3M sh
    short* wob  = wqkv + (size_t)3*Dm*Dm;            // 1M sh

    dim3 qgrid(3072/128, Rm/128);  // (24, 32)
    dim3 pgrid(Dm/64,    Rm/128);  // (16, 32): proj BN=64 (round-4 proven)
    dim3 agrid(32, 32);            // (bh, xi), balanced qt table, 256-thr

    convert_w<<<4096, 256, 0, stream>>>(wq, wk, wv, wo, wqkv, wob);

    // ---- Block 1 ----
    ln_kernel<<<Rm, 256, 0, stream>>>(x, ln1, lnb);
    gemm_mfma<128, 1><<<qgrid, 256, 0, stream>>>(lnb, wqkv, nullptr, nullptr, qk, vtg, Rm, 3072, Dm);
    attn_mfma<<<agrid, 256, 0, stream>>>(qk, vtg, ctxb);
    gemm_mfma<64, 0><<<pgrid, 256, 0, stream>>>(ctxb, wob, bo, x, out, nullptr, Rm, Dm, Dm);

    // ---- Block 2 (same weights, ln2) ----
    ln_kernel<<<Rm, 256, 0, stream>>>(out, ln2, lnb);
    gemm_mfma<128, 1><<<qgrid, 256, 0, stream>>>(lnb, wqkv, nullptr, nullptr, qk, vtg, Rm, 3072, Dm);
    attn_mfma<<<agrid, 256, 0, stream>>>(qk, vtg, ctxb);
    gemm_mfma<64, 0><<<pgrid, 256, 0, stream>>>(ctxb, wob, bo, out, out, nullptr, Rm, Dm, Dm);
}

// Round 10
// 261.692 us; speedup vs baseline: 1.1505x; 1.0877x over previous
//
#include <hip/hip_runtime.h>
#include <hip/hip_bf16.h>
#include <math.h>

#define Dm 1024
#define Tm 2048
#define Bm 2
#define Hm 16
#define HDm 64
#define Rm (Bm*Tm)   // 4096 rows
#define QKS 2048     // q|k row stride (dense, V split out)

typedef __attribute__((ext_vector_type(8))) short sh8;      // 8 bf16 (4 VGPRs)
typedef __attribute__((ext_vector_type(4))) float f32x4;    // 16x16 C/D frag
typedef __attribute__((ext_vector_type(16))) float f32x16;  // 32x32 C/D frag

#define AS1(p) ((const __attribute__((address_space(1))) void*)(p))
#define AS3(p) ((__attribute__((address_space(3))) void*)(p))

// fp32 -> bf16 bits, round-to-nearest-even
__device__ __forceinline__ short f2bs(float f) {
    union { float f; unsigned u; } v; v.f = f;
    unsigned r = v.u + 0x7FFFu + ((v.u >> 16) & 1u);
    return (short)(r >> 16);
}

// ---------------- fused: LN (block1) + weight convert ------------------
// blocks 0..4095: LayerNorm row; blocks 4096..8191: weight convert.
// wq pre-scaled by 0.125 (1/sqrt(64)): exact (pow2 commutes with rounding).
__global__ __launch_bounds__(256) void ln_conv(const float* __restrict__ x,
                                               const float* __restrict__ scale,
                                               short* __restrict__ out,
                                               const float* __restrict__ wq,
                                               const float* __restrict__ wk,
                                               const float* __restrict__ wv,
                                               const float* __restrict__ wo,
                                               short* __restrict__ wqkv,
                                               short* __restrict__ wob) {
    __shared__ float red[8];
    if (blockIdx.x >= 4096) {
        int idx = ((blockIdx.x - 4096) * 256 + threadIdx.x) * 4;  // 4M total
        const int M1 = 1 << 20;
        const float* src; short* dst; int off; float sc = 1.0f;
        if (idx < M1)           { src = wq; dst = wqkv;          off = idx; sc = 0.125f; }
        else if (idx < 2*M1)    { src = wk; dst = wqkv + M1;     off = idx - M1; }
        else if (idx < 3*M1)    { src = wv; dst = wqkv + 2*M1;   off = idx - 2*M1; }
        else                    { src = wo; dst = wob;           off = idx - 3*M1; }
        float4 v = *(const float4*)(src + off);
        short4 o;
        o.x = f2bs(v.x*sc); o.y = f2bs(v.y*sc); o.z = f2bs(v.z*sc); o.w = f2bs(v.w*sc);
        *(short4*)(dst + off) = o;
        return;
    }
    int row = blockIdx.x;
    int t = threadIdx.x;
    const float4* xr = (const float4*)(x + (size_t)row * Dm);
    float4 v = xr[t];
    float s  = v.x + v.y + v.z + v.w;
    float ss = v.x*v.x + v.y*v.y + v.z*v.z + v.w*v.w;
    #pragma unroll
    for (int off = 32; off; off >>= 1) {
        s  += __shfl_xor(s, off);
        ss += __shfl_xor(ss, off);
    }
    int wave = t >> 6, lane = t & 63;
    if (lane == 0) { red[wave*2] = s; red[wave*2+1] = ss; }
    __syncthreads();
    s  = red[0] + red[2] + red[4] + red[6];
    ss = red[1] + red[3] + red[5] + red[7];
    float mean = s * (1.0f / Dm);
    float var  = ss * (1.0f / Dm) - mean * mean;
    float rstd = 1.0f / sqrtf(var + 1e-5f);
    float4 sc = ((const float4*)scale)[t];
    short4 o;
    o.x = f2bs(sc.x * ((v.x - mean) * rstd) + sc.x);
    o.y = f2bs(sc.y * ((v.y - mean) * rstd) + sc.y);
    o.z = f2bs(sc.z * ((v.z - mean) * rstd) + sc.z);
    o.w = f2bs(sc.w * ((v.w - mean) * rstd) + sc.w);
    ((short4*)(out + (size_t)row * Dm))[t] = o;
}

// ---------------- LayerNorm: one block (256 thr) per row, bf16 out ------
__global__ __launch_bounds__(256) void ln_kernel(const float* __restrict__ x,
                                                 const float* __restrict__ scale,
                                                 short* __restrict__ out) {
    int row = blockIdx.x;
    int t = threadIdx.x;
    const float4* xr = (const float4*)(x + (size_t)row * Dm);
    float4 v = xr[t];
    float s  = v.x + v.y + v.z + v.w;
    float ss = v.x*v.x + v.y*v.y + v.z*v.z + v.w*v.w;
    #pragma unroll
    for (int off = 32; off; off >>= 1) {
        s  += __shfl_xor(s, off);
        ss += __shfl_xor(ss, off);
    }
    __shared__ float red[8];
    int wave = t >> 6, lane = t & 63;
    if (lane == 0) { red[wave*2] = s; red[wave*2+1] = ss; }
    __syncthreads();
    s  = red[0] + red[2] + red[4] + red[6];
    ss = red[1] + red[3] + red[5] + red[7];
    float mean = s * (1.0f / Dm);
    float var  = ss * (1.0f / Dm) - mean * mean;
    float rstd = 1.0f / sqrtf(var + 1e-5f);
    float4 sc = ((const float4*)scale)[t];
    short4 o;
    o.x = f2bs(sc.x * ((v.x - mean) * rstd) + sc.x);
    o.y = f2bs(sc.y * ((v.y - mean) * rstd) + sc.y);
    o.z = f2bs(sc.z * ((v.z - mean) * rstd) + sc.z);
    o.w = f2bs(sc.w * ((v.w - mean) * rstd) + sc.w);
    ((short4*)(out + (size_t)row * Dm))[t] = o;
}

// ---------------- MFMA GEMM (m97 structure, BK=64): C = A @ B^T --------
// BK=64: per K-step 8 global_load_lds + 16 ds_read_b128 + 32 MFMA/wave,
// 16 steps (was 32) -> half the barrier+vmcnt(0) drains. 8-slot XOR
// swizzle per 128B row (same family as attn's proven K staging).
// MODE 0: float out + bias + residual (proj GEMM)
// MODE 1: QKV gemm: n<2048 -> bf16 into qk buffer (stride 2048);
//         n>=2048 -> V stored transposed per head AND key-permuted within
//         each 16-key group (pi: quads 1<->2) -> vtg[bh][d][key'].
template<int BN, int MODE>
__global__ __launch_bounds__(256) void gemm_mfma(const short* __restrict__ A,
                                                 const short* __restrict__ B,
                                                 const float* __restrict__ bias,
                                                 const float* __restrict__ res,
                                                 void* __restrict__ Cv,
                                                 short* __restrict__ Vt,
                                                 int M, int N, int K) {
    __shared__ short As[128*64];
    __shared__ short Bs[BN*64];
    __shared__ short Tb[(MODE==1) ? 4*16*68 : 4];   // per-wave transpose bounce
    const int NJ = BN / 32;            // 16x16 j-tiles per wave
    int t = threadIdx.x;
    int lane = t & 63, w = t >> 6;
    int l = lane & 15, quad = lane >> 4;
    int wm = (w & 1) * 64, wn = (w >> 1) * (BN/2);
    int m0 = blockIdx.y * 128, n0 = blockIdx.x * BN;

    f32x4 acc[4][NJ];
    #pragma unroll
    for (int i = 0; i < 4; i++)
        #pragma unroll
        for (int j = 0; j < NJ; j++)
            acc[i][j] = (f32x4){0.f,0.f,0.f,0.f};

    for (int k0 = 0; k0 < K; k0 += 64) {
        __syncthreads();
        #pragma unroll
        for (int p = 0; p < 4; p++) {            // A tile: 128 rows x 64
            int off = p*4096 + t*16;             // LDS byte offset
            int row = off >> 7;
            int c = ((off >> 4) & 7) ^ (row & 7);
            const short* ga = A + (size_t)(m0 + row) * K + k0 + c*8;
            __builtin_amdgcn_global_load_lds(AS1(ga), AS3((char*)As + off), 16, 0, 0);
        }
        #pragma unroll
        for (int p = 0; p < BN/32; p++) {        // B tile: BN rows x 64
            int off = p*4096 + t*16;
            int row = off >> 7;
            int c = ((off >> 4) & 7) ^ (row & 7);
            const short* gb = B + (size_t)(n0 + row) * K + k0 + c*8;
            __builtin_amdgcn_global_load_lds(AS1(gb), AS3((char*)Bs + off), 16, 0, 0);
        }
        __syncthreads();
        sh8 a0[4], a1[4], b0[NJ], b1[NJ];
        #pragma unroll
        for (int i = 0; i < 4; i++) {
            int m = wm + i*16 + l;
            const char* ar = (const char*)As + m*128;
            int sw = m & 7;
            a0[i] = *(const sh8*)(ar + ((quad ^ sw) * 16));
            a1[i] = *(const sh8*)(ar + (((4 + quad) ^ sw) * 16));
        }
        #pragma unroll
        for (int j = 0; j < NJ; j++) {
            int n = wn + j*16 + l;
            const char* br = (const char*)Bs + n*128;
            int sw = n & 7;
            b0[j] = *(const sh8*)(br + ((quad ^ sw) * 16));
            b1[j] = *(const sh8*)(br + (((4 + quad) ^ sw) * 16));
        }
        #pragma unroll
        for (int i = 0; i < 4; i++)
            #pragma unroll
            for (int j = 0; j < NJ; j++) {
                acc[i][j] = __builtin_amdgcn_mfma_f32_16x16x32_bf16(a0[i], b0[j], acc[i][j], 0, 0, 0);
                acc[i][j] = __builtin_amdgcn_mfma_f32_16x16x32_bf16(a1[i], b1[j], acc[i][j], 0, 0, 0);
            }
    }
    // epilogue
    if (MODE == 0) {
        #pragma unroll
        for (int i = 0; i < 4; i++)
            #pragma unroll
            for (int j = 0; j < NJ; j++)
                #pragma unroll
                for (int r = 0; r < 4; r++) {
                    int m = m0 + wm + i*16 + quad*4 + r;
                    int n = n0 + wn + j*16 + l;
                    float vv = acc[i][j][r] + bias[n] + res[(size_t)m * N + n];
                    ((float*)Cv)[(size_t)m * N + n] = vv;
                }
    } else {
        if (n0 < 2048) {
            // q,k part: bf16 store at dense stride 2048
            #pragma unroll
            for (int i = 0; i < 4; i++)
                #pragma unroll
                for (int j = 0; j < NJ; j++)
                    #pragma unroll
                    for (int r = 0; r < 4; r++) {
                        int m = m0 + wm + i*16 + quad*4 + r;
                        int n = n0 + wn + j*16 + l;
                        ((short*)Cv)[(size_t)m * QKS + n] = f2bs(acc[i][j][r]);
                    }
        } else {
            // V part: transpose + pi-permute -> vtg[bh][d][key']
            // pi swaps quads 1<->2 per 16-key group: quad' = bit-swap(quad).
            int bq = m0 >> 11;                    // batch
            int key0 = (m0 & 2047) + wm;          // wave's key base
            int h = (n0 + wn - 2048) >> 6;        // wave covers exactly one head
            int quad2 = ((quad & 1) << 1) | (quad >> 1);
            short* vout = Vt + ((size_t)(bq*Hm + h) * HDm) * Tm + key0;
            #pragma unroll
            for (int j = 0; j < NJ; j++) {
                #pragma unroll
                for (int i = 0; i < 4; i++) {
                    short4 o;
                    o.x = f2bs(acc[i][j][0]); o.y = f2bs(acc[i][j][1]);
                    o.z = f2bs(acc[i][j][2]); o.w = f2bs(acc[i][j][3]);
                    *(short4*)&Tb[w*(16*68) + l*68 + i*16 + quad2*4] = o;
                }
                #pragma unroll
                for (int st = 0; st < 2; st++) {
                    int rr = st*8 + (lane >> 3);
                    int cc = lane & 7;
                    sh8 vv = *(const sh8*)&Tb[w*(16*68) + rr*68 + cc*8];
                    *(sh8*)(vout + (size_t)(j*16 + rr) * Tm + cc*8) = vv;
                }
            }
        }
    }
}

// ---------------- MFMA flash attention, 32x32 S^T, lane-local P ---------
// v9 (unchanged, proven): key-split waves, 256-thr blocks, wave (qh,kh)
// owns q-half qh and key-half kh. 16 waves/CU peak at 40 KB LDS.
// Pipeline per iter: exp/pack(kc) -> barrier -> STAGE_K(kc+2) ->
// STAGE_V(kc+1) -> QK(kc+1) -> PV(kc). K 3-ring, V 2-ring.
__global__ __launch_bounds__(256) void attn_mfma(const short* __restrict__ qk,
                                                 const short* __restrict__ vtg,
                                                 short* __restrict__ ctx) {
    __shared__ short Kl[3][64*64];     // 24 KB: XOR-swizzled, 3-ring
    __shared__ short Vl[2][64*64];     // 16 KB: V^T permuted, swizzled, dbuf
    int t = threadIdx.x;               // 0..255
    int lane = t & 63, w = t >> 6;     // 4 waves
    int qh = w & 1, kh = w >> 1;       // q-half, key-half
    int l31 = lane & 31, hi = lane >> 5;
    int bh = blockIdx.x;               // 0..31 (XCD = bh%8)
    int xi = blockIdx.y;               // 0..31
    int cc0 = xi & 7, kk0 = xi >> 3;
    int qt = (kk0 == 0) ? cc0 : (kk0 == 1) ? (15 - cc0)
           : (kk0 == 2) ? (16 + cc0) : (31 - cc0);
    int b = bh >> 4, h = bh & 15;
    size_t rbase = (size_t)b * Tm;
    const short* qp0 = qk + rbase * QKS + h*HDm;
    const short* kp0 = qp0 + Dm;
    const short* vh  = vtg + ((size_t)bh * HDm) * Tm;
    int qtbase = qt * 64;
    int qrow = qtbase + qh*32 + l31;

    // Q B-frags: qf[s] = Q[q=l31 of half qh][d = s*16 + hi*8 + j]
    sh8 qf[4];
    {
        const short* qp = qp0 + (size_t)qrow * QKS + hi*8;
        qf[0] = *(const sh8*)qp;
        qf[1] = *(const sh8*)(qp + 16);
        qf[2] = *(const sh8*)(qp + 32);
        qf[3] = *(const sh8*)(qp + 48);
    }

    f32x16 O0, O1;
    #pragma unroll
    for (int i = 0; i < 16; i++) { O0[i] = 0.f; O1[i] = 0.f; }
    float ps = 0.f;

    // ---- staging (256 thr stage 8KB K + 8KB V per chunk, 2 loads each) --
    int trow = t >> 3;                       // 0..31
    int c8 = ((t & 7) ^ (trow & 7)) * 8;     // pre-swizzled source chunk
    int ldsoff = t * 16;                     // bytes, 0..4080
    const short* gkp = kp0 + (size_t)trow * QKS + c8;
    const short* gvp = vh + (size_t)trow * Tm + c8;

#define STAGE_K(KD) do { \
    __builtin_amdgcn_global_load_lds(AS1(gkp),                  AS3((char*)(KD) + ldsoff), 16, 0, 0); \
    __builtin_amdgcn_global_load_lds(AS1(gkp + (size_t)32*QKS), AS3((char*)(KD) + 4096 + ldsoff), 16, 0, 0); \
    gkp += (size_t)64*QKS; } while (0)

#define STAGE_V(VD) do { \
    __builtin_amdgcn_global_load_lds(AS1(gvp),                 AS3((char*)(VD) + ldsoff), 16, 0, 0); \
    __builtin_amdgcn_global_load_lds(AS1(gvp + (size_t)32*Tm), AS3((char*)(VD) + 4096 + ldsoff), 16, 0, 0); \
    gvp += 64; } while (0)

// QK for this wave's key-half from KBUF into S0 (keys kh*32 + l31)
#define QKCOMP(KBUF) do { \
    const char* kr_ = (const char*)(KBUF) + (kh*32 + l31)*128; \
    int sw_ = l31 & 7; \
    f32x16 c_; \
    _Pragma("unroll") for (int i_ = 0; i_ < 16; i_++) c_[i_] = 0.f; \
    _Pragma("unroll") for (int s_ = 0; s_ < 4; s_++) { \
        sh8 kf_ = *(const sh8*)(kr_ + (((s_*2 + hi) ^ sw_) * 16)); \
        c_ = __builtin_amdgcn_mfma_f32_32x32x16_bf16(kf_, qf[s_], c_, 0, 0, 0); } \
    S0 = c_; \
} while (0)

    // ---- prologue ----
    STAGE_K(Kl[0]);
    STAGE_V(Vl[0]);
    if (qt >= 1) STAGE_K(Kl[1]);
    __syncthreads();

    f32x16 S0;
    QKCOMP(Kl[0]);

    int bcur = 0;                      // K-ring index of chunk kc
    for (int kc = 0; kc <= qt; kc++) {
        int kbase = kc * 64;
        // ---- exp/pack chunk kc (this wave: keys kbase + kh*32 + 0..31) --
        sh8 pa[2];
        {
            bool needmask = (kbase + kh*32 + 31 > qtbase + qh*32);
            float p_[16];
            if (needmask) {
                #pragma unroll
                for (int r = 0; r < 16; r++) {
                    int key_r = kbase + kh*32 + (r&3) + 8*(r>>2) + 4*hi;
                    p_[r] = (key_r > qrow) ? 0.f : __expf(S0[r]);
                }
            } else {
                #pragma unroll
                for (int r = 0; r < 16; r++) p_[r] = __expf(S0[r]);
            }
            ps += (((p_[0]+p_[1])+(p_[2]+p_[3])) + ((p_[4]+p_[5])+(p_[6]+p_[7])))
                + (((p_[8]+p_[9])+(p_[10]+p_[11])) + ((p_[12]+p_[13])+(p_[14]+p_[15])));
            #pragma unroll
            for (int gg = 0; gg < 2; gg++) {
                union { __hip_bfloat162 h2[4]; sh8 s8; } u;
                u.h2[0] = __float22bfloat162_rn({p_[gg*8+0], p_[gg*8+1]});
                u.h2[1] = __float22bfloat162_rn({p_[gg*8+2], p_[gg*8+3]});
                u.h2[2] = __float22bfloat162_rn({p_[gg*8+4], p_[gg*8+5]});
                u.h2[3] = __float22bfloat162_rn({p_[gg*8+6], p_[gg*8+7]});
                pa[gg] = u.s8;
            }
        }

        // ---- barrier: drains K(kc+1) and V(kc), both issued last iter ----
        __syncthreads();

        // ---- prefetch 2-ahead K, 1-ahead V (drained NEXT barrier) ----
        int bnext = (bcur == 2) ? 0 : bcur + 1;       // ring idx of kc+1
        if (kc + 2 <= qt) {
            int bnext2 = (bnext == 2) ? 0 : bnext + 1;
            STAGE_K(Kl[bnext2]);
        }
        if (kc + 1 <= qt) STAGE_V(Vl[(kc + 1) & 1]);

        // ---- QK(kc+1): overlaps PV(kc) in the MFMA pipe ----
        if (kc < qt) QKCOMP(Kl[bnext]);

        // ---- O += P V over this wave's key-half (groups G = kh*2, kh*2+1)
        const char* Vb = (const char*)Vl[kc & 1];
        int G0 = kh * 2;
        {
            const char* vr = Vb + l31*128;
            int sw = l31 & 7;
            sh8 v0 = *(const sh8*)(vr + ((((G0  )*2 + hi) ^ sw) * 16));
            sh8 v1 = *(const sh8*)(vr + ((((G0+1)*2 + hi) ^ sw) * 16));
            O0 = __builtin_amdgcn_mfma_f32_32x32x16_bf16(pa[0], v0, O0, 0, 0, 0);
            O0 = __builtin_amdgcn_mfma_f32_32x32x16_bf16(pa[1], v1, O0, 0, 0, 0);
        }
        {
            const char* vr = Vb + (32 + l31)*128;
            int sw = l31 & 7;
            sh8 v0 = *(const sh8*)(vr + ((((G0  )*2 + hi) ^ sw) * 16));
            sh8 v1 = *(const sh8*)(vr + ((((G0+1)*2 + hi) ^ sw) * 16));
            O1 = __builtin_amdgcn_mfma_f32_32x32x16_bf16(pa[0], v0, O1, 0, 0, 0);
            O1 = __builtin_amdgcn_mfma_f32_32x32x16_bf16(pa[1], v1, O1, 0, 0, 0);
        }
        bcur = bnext;
    }
#undef STAGE_K
#undef STAGE_V
#undef QKCOMP

    // ---- epilogue: combine key-halves via LDS (reuse Kl/Vl), store -----
    ps += __shfl_xor(ps, 32);          // per-q-col denominator (this half)
    __syncthreads();                   // all compute done; LDS reusable
    float* Lo  = (float*)Kl;           // 16 KB: [qh][q 0..31][d 0..63]
    float* Lps = (float*)Vl;           // 64 floats
    if (kh == 1) {
        #pragma unroll
        for (int r = 0; r < 16; r++) {
            int rl = (r&3) + 8*(r>>2) + 4*hi;
            Lo[qh*2048 + rl*64 + l31]      = O0[r];
            Lo[qh*2048 + rl*64 + 32 + l31] = O1[r];
        }
        if (hi == 0) Lps[qh*32 + l31] = ps;
    }
    __syncthreads();
    if (kh == 0) {
        float pst = ps + Lps[qh*32 + l31];
        float inv_own = 1.0f / pst;
        short* cp = ctx + (rbase + qtbase + qh*32) * Dm + h*HDm + l31;
        #pragma unroll
        for (int r = 0; r < 16; r++) {
            int rl = (r&3) + 8*(r>>2) + 4*hi;
            float inv = __shfl(inv_own, rl);
            cp[(size_t)rl * Dm]      = f2bs((O0[r] + Lo[qh*2048 + rl*64 + l31]) * inv);
            cp[(size_t)rl * Dm + 32] = f2bs((O1[r] + Lo[qh*2048 + rl*64 + 32 + l31]) * inv);
        }
    }
}

// ---------------- launch ----------------
extern "C" void kernel_launch(void* const* d_in, const int* in_sizes, int n_in,
                              void* d_out, int out_size, void* d_ws, size_t ws_size,
                              hipStream_t stream) {
    const float* x   = (const float*)d_in[0];
    const float* wq  = (const float*)d_in[1];
    const float* wk  = (const float*)d_in[2];
    const float* wv  = (const float*)d_in[3];
    const float* wo  = (const float*)d_in[4];
    const float* bo  = (const float*)d_in[5];
    const float* ln1 = (const float*)d_in[6];
    const float* ln2 = (const float*)d_in[7];
    float* out = (float*)d_out;

    short* lnb  = (short*)d_ws;                      // 4096*1024 = 4M sh
    short* ctxb = lnb  + (size_t)Rm*Dm;              // 4M sh
    short* qk   = ctxb + (size_t)Rm*Dm;              // 8M sh
    short* vtg  = qk   + (size_t)Rm*QKS;             // 4M sh
    short* wqkv = vtg  + (size_t)Bm*Hm*HDm*Tm;       // 3M sh
    short* wob  = wqkv + (size_t)3*Dm*Dm;            // 1M sh

    dim3 qgrid(3072/128, Rm/128);  // (24, 32)
    dim3 pgrid(Dm/64,    Rm/128);  // (16, 32): proj BN=64
    dim3 agrid(32, 32);            // (bh, xi), balanced qt table, 256-thr

    // ---- Block 1 (LN1 fused with weight convert) ----
    ln_conv<<<8192, 256, 0, stream>>>(x, ln1, lnb, wq, wk, wv, wo, wqkv, wob);
    gemm_mfma<128, 1><<<qgrid, 256, 0, stream>>>(lnb, wqkv, nullptr, nullptr, qk, vtg, Rm, 3072, Dm);
    attn_mfma<<<agrid, 256, 0, stream>>>(qk, vtg, ctxb);
    gemm_mfma<64, 0><<<pgrid, 256, 0, stream>>>(ctxb, wob, bo, x, out, nullptr, Rm, Dm, Dm);

    // ---- Block 2 (same weights, ln2) ----
    ln_kernel<<<Rm, 256, 0, stream>>>(out, ln2, lnb);
    gemm_mfma<128, 1><<<qgrid, 256, 0, stream>>>(lnb, wqkv, nullptr, nullptr, qk, vtg, Rm, 3072, Dm);
    attn_mfma<<<agrid, 256, 0, stream>>>(qk, vtg, ctxb);
    gemm_mfma<64, 0><<<pgrid, 256, 0, stream>>>(ctxb, wob, bo, out, out, nullptr, Rm, Dm, Dm);
}